// Round 15
// baseline (95.205 us; speedup 1.0000x reference)
//
#include <hip/hip_runtime.h>
#include <hip/hip_bf16.h>

#define BB   256
#define NIN  1152
#define OO   10
#define IL   8
#define OL   16
#define ROW  (OO*OL)      // 160
#define EPSQ 1e-7f
#define NTT  32           // n per build2 block
#define BT2  16           // b per build2 block
#define NCH2 (NIN/NTT)    // 36 psum chunks

typedef unsigned short ushx8 __attribute__((ext_vector_type(8)));

__device__ __forceinline__ float bf2f(unsigned short h) {
    unsigned u = ((unsigned)h) << 16;
    return __builtin_bit_cast(float, u);
}

// K1: build u_hat (bf16) AND psum[nc][b][160] = sum over the block's 32 n of
// u (fp32) — iter0's reduction falls out free because each thread owns a fixed
// (b, oct) and loops over n (no cross-thread reduce; +8 VGPR only).
// Block 320 = 16 b-lanes x 20 octs. Grid (36, 16). w staged 4n at a time with
// the verified o-parity swizzle (measured 0 conflicts); x read from global
// (same 16B address across the 20 oct-lanes -> broadcast).
__global__ __launch_bounds__(320) void caps_build2(
    const float* __restrict__ x, const float* __restrict__ w,
    unsigned short* __restrict__ u, float* __restrict__ psum)
{
    __shared__ float4 wl4[4][321];      // 4n x 320 float4 + pad
    const int t    = threadIdx.x;
    const int bloc = t / 20;            // 0..15
    const int oct  = t - bloc * 20;     // 0..19
    const int o    = oct >> 1;
    const int k8   = oct & 1;
    const int p    = o & 1;
    const int n0   = blockIdx.x * NTT;
    const int b    = blockIdx.y * BT2 + bloc;

    const float* xb = x + ((size_t)b * NIN + n0) * 8;
    unsigned short* ub = u + ((size_t)b * NIN + n0) * ROW + o * OL + k8 * 8;

    float ps[8];
    #pragma unroll
    for (int j = 0; j < 8; ++j) ps[j] = 0.f;

    for (int sub = 0; sub < 8; ++sub) {
        __syncthreads();
        // stage w for 4 n's (o-parity swizzle), coalesced: 1280 float4 / 320 thr
        const float4* wg = reinterpret_cast<const float4*>(w)
                         + (size_t)(n0 + sub * 4) * 320;
        #pragma unroll
        for (int jj = 0; jj < 4; ++jj) {
            const int j   = t + jj * 320;
            const int row = j / 320;
            const int lin = j - row * 320;
            const int o2  = lin >> 5;
            const int rem = lin & 31;
            const int i2  = rem >> 2;
            const int kh  = rem & 3;
            wl4[row][(o2 << 5) | ((i2 ^ (o2 & 1)) << 2) | kh] = wg[j];
        }
        __syncthreads();

        #pragma unroll
        for (int nn = 0; nn < 4; ++nn) {
            const int nrel = sub * 4 + nn;
            const float4 x0 = *reinterpret_cast<const float4*>(xb + nrel * 8);
            const float4 x1 = *reinterpret_cast<const float4*>(xb + nrel * 8 + 4);
            const float xv[IL] = {x0.x, x0.y, x0.z, x0.w, x1.x, x1.y, x1.z, x1.w};

            float acc[8];
            #pragma unroll
            for (int j = 0; j < 8; ++j) acc[j] = 0.f;

            const float4* wbase = &wl4[nn][(o << 5) | (k8 << 1)];
            #pragma unroll
            for (int i = 0; i < IL; ++i) {
                const float4 wlo = wbase[(i ^ p) << 2];
                const float4 whi = wbase[((i ^ p) << 2) | 1];
                acc[0] = fmaf(wlo.x, xv[i], acc[0]);
                acc[1] = fmaf(wlo.y, xv[i], acc[1]);
                acc[2] = fmaf(wlo.z, xv[i], acc[2]);
                acc[3] = fmaf(wlo.w, xv[i], acc[3]);
                acc[4] = fmaf(whi.x, xv[i], acc[4]);
                acc[5] = fmaf(whi.y, xv[i], acc[5]);
                acc[6] = fmaf(whi.z, xv[i], acc[6]);
                acc[7] = fmaf(whi.w, xv[i], acc[7]);
            }

            union { ushx8 v; __hip_bfloat162 h[4]; } pk;
            #pragma unroll
            for (int j = 0; j < 4; ++j)
                pk.h[j] = __float22bfloat162_rn(make_float2(acc[2*j], acc[2*j+1]));
            *reinterpret_cast<ushx8*>(ub + (size_t)nrel * ROW) = pk.v;

            #pragma unroll
            for (int j = 0; j < 8; ++j) ps[j] += acc[j];
        }
    }

    float* pp = psum + ((size_t)blockIdx.x * BB + b) * ROW + oct * 8;
    *reinterpret_cast<float4*>(pp)     = make_float4(ps[0], ps[1], ps[2], ps[3]);
    *reinterpret_cast<float4*>(pp + 4) = make_float4(ps[4], ps[5], ps[6], ps[7]);
}

// K2: sum psum chunks, *0.1 + bias, squash -> v0. (verified round-9 structure)
__global__ __launch_bounds__(192) void caps_squash0(
    const float* __restrict__ psum, const float* __restrict__ bias,
    float* __restrict__ v0)
{
    const int t = threadIdx.x;
    if (t >= ROW) return;
    const int b = blockIdx.x;

    float s0 = 0.f, s1 = 0.f, s2 = 0.f, s3 = 0.f;
    const float* pt = psum + (size_t)b * ROW + t;
    #pragma unroll
    for (int ch = 0; ch < NCH2; ch += 4) {
        s0 += pt[(size_t)(ch + 0) * BB * ROW];
        s1 += pt[(size_t)(ch + 1) * BB * ROW];
        s2 += pt[(size_t)(ch + 2) * BB * ROW];
        s3 += pt[(size_t)(ch + 3) * BB * ROW];
    }
    const float s = 0.1f * ((s0 + s1) + (s2 + s3)) + bias[t];

    float d = s * s;
    d += __shfl_xor(d, 1, 16);
    d += __shfl_xor(d, 2, 16);
    d += __shfl_xor(d, 4, 16);
    d += __shfl_xor(d, 8, 16);
    const float f = d / ((1.f + d) * sqrtf(d + EPSQ));
    v0[(size_t)b * ROW + t] = f * s;
}

// K3: routing iterations 1,2 fused (iter0's sweep eliminated — v0 comes from
// caps_squash0). EXACT round-8/14 verified code path: 768 thr = 12 waves,
// 80 VGPR, no spill; lane q of each 4-lane group owns row chunks {q+4j}.
__global__ __launch_bounds__(768) void caps_route2(
    const unsigned short* __restrict__ u, const float* __restrict__ bias,
    const float* __restrict__ v0g, float* __restrict__ outv)
{
    __shared__ float lds[12][ROW];
    __shared__ float vbuf[ROW];
    const int t  = threadIdx.x;
    const int q  = t & 3;
    const int g  = t >> 2;     // 0..191
    const int wv = t >> 6;     // 0..11
    const int b  = blockIdx.x;
    const unsigned short* ub = u + (size_t)b * NIN * ROW;

    float bsv = 0.f;
    float vprev = 0.f;
    if (t < ROW) {
        bsv = bias[t];
        const float v = v0g[(size_t)b * ROW + t];
        vbuf[t] = v;
        vprev = v;
    }
    __syncthreads();

    #pragma unroll
    for (int iter = 1; iter < 3; ++iter) {
        float sp[5][8];
        #pragma unroll
        for (int j = 0; j < 5; ++j)
            #pragma unroll
            for (int e = 0; e < 8; ++e) sp[j][e] = 0.f;

        float vs[5][8];
        #pragma unroll
        for (int j = 0; j < 5; ++j) {
            #pragma unroll
            for (int e = 0; e < 8; ++e) vs[j][e] = vbuf[(q + 4 * j) * 8 + e];
        }

        for (int m = 0; m < 6; ++m) {
            const unsigned short* un = ub + (size_t)(g + m * 192) * ROW;
            float uf[5][8];
            #pragma unroll
            for (int j = 0; j < 5; ++j) {
                const ushx8 raw = *reinterpret_cast<const ushx8*>(un + (q + 4 * j) * 8);
                #pragma unroll
                for (int e = 0; e < 8; ++e) uf[j][e] = bf2f(raw[e]);
            }

            // own-parity dots (half-k), combine halves, then swap parity
            float d[5], dd[5];
            #pragma unroll
            for (int j = 0; j < 5; ++j) {
                float acc = uf[j][0] * vs[j][0];
                #pragma unroll
                for (int e = 1; e < 8; ++e) acc = fmaf(uf[j][e], vs[j][e], acc);
                acc += __shfl_xor(acc, 1, 4);   // h=0 + h=1 -> full 16-k dot
                d[j] = acc;
            }
            #pragma unroll
            for (int j = 0; j < 5; ++j) dd[j] = __shfl_xor(d[j], 2, 4);

            float mx = fmaxf(d[0], dd[0]);
            #pragma unroll
            for (int j = 1; j < 5; ++j) mx = fmaxf(mx, fmaxf(d[j], dd[j]));
            float se = 0.f, e_[5];
            #pragma unroll
            for (int j = 0; j < 5; ++j) {
                e_[j] = __expf(d[j] - mx);
                se += e_[j] + __expf(dd[j] - mx);
            }
            const float r = 1.f / se;
            #pragma unroll
            for (int j = 0; j < 5; ++j) {
                const float c = e_[j] * r;
                #pragma unroll
                for (int e = 0; e < 8; ++e)
                    sp[j][e] = fmaf(c, uf[j][e], sp[j][e]);
            }
        }

        // butterfly over the 16 groups of each wave (masks preserve q)
        #pragma unroll
        for (int j = 0; j < 5; ++j)
            #pragma unroll
            for (int e = 0; e < 8; ++e) {
                #pragma unroll
                for (int msk = 4; msk <= 32; msk <<= 1)
                    sp[j][e] += __shfl_xor(sp[j][e], msk);
            }
        if ((t & 63) < 4) {
            #pragma unroll
            for (int j = 0; j < 5; ++j)
                #pragma unroll
                for (int e = 0; e < 8; ++e)
                    lds[wv][(q + 4 * j) * 8 + e] = sp[j][e];
        }
        __syncthreads();

        if (t < ROW) {
            float ssum = 0.f;
            #pragma unroll
            for (int wvi = 0; wvi < 12; ++wvi) ssum += lds[wvi][t];
            const float sv = ssum + bsv;

            float dq = sv * sv;
            dq += __shfl_xor(dq, 1, 16);
            dq += __shfl_xor(dq, 2, 16);
            dq += __shfl_xor(dq, 4, 16);
            dq += __shfl_xor(dq, 8, 16);
            const float f = dq / ((1.f + dq) * sqrtf(dq + EPSQ));
            const float v = f * sv;

            if (iter == 1) { vbuf[t] = v + vprev; }
            else           { outv[(size_t)b * ROW + t] = v; }
        }
        __syncthreads();
    }
}

extern "C" void kernel_launch(void* const* d_in, const int* in_sizes, int n_in,
                              void* d_out, int out_size, void* d_ws, size_t ws_size,
                              hipStream_t stream) {
    const float* x    = (const float*)d_in[0]; // (B, NIN, 8, 1)
    const float* w    = (const float*)d_in[1]; // (1, NIN, O, 8, 16)
    const float* bias = (const float*)d_in[2]; // (1, 1, O, 16, 1)
    float* out = (float*)d_out;                // (B, 1, O, 16, 1)

    unsigned short* u = (unsigned short*)d_ws;                  // 94.4 MB bf16
    float* psum = (float*)((char*)d_ws + (size_t)BB * NIN * ROW * 2); // 5.9 MB
    float* v0   = psum + (size_t)NCH2 * BB * ROW;               // 160 KB

    caps_build2<<<dim3(NIN / NTT, BB / BT2), 320, 0, stream>>>(x, w, u, psum);
    caps_squash0<<<BB, 192, 0, stream>>>(psum, bias, v0);
    caps_route2<<<BB, 768, 0, stream>>>(u, bias, v0, out);
}

// Round 16
// 81.811 us; speedup vs baseline: 1.1637x; 1.1637x over previous
//
#include <hip/hip_runtime.h>
#include <hip/hip_bf16.h>

#define BB   256
#define NIN  1152
#define OO   10
#define IL   8
#define OL   16
#define ROW  (OO*OL)      // 160
#define EPSQ 1e-7f
#define NTT  16           // n per build2 block
#define BT2  16           // b per build2 block
#define NCH2 (NIN/NTT)    // 72 psum chunks

typedef unsigned short ushx8 __attribute__((ext_vector_type(8)));

__device__ __forceinline__ float bf2f(unsigned short h) {
    unsigned u = ((unsigned)h) << 16;
    return __builtin_bit_cast(float, u);
}

// K1: build u_hat (bf16) AND psum[nc][b][160] = fp32 sum of u over the block's
// 16 n (iter0's reduction, free in registers: thread owns fixed (b, oct)).
// Block 320 = 16 b-lanes x 20 octs. Grid (72, 16) = 1152 blocks (4.5/CU).
// w staged 4n at a time at STRIDE 33 float4/o: bank-group = (o+2k8+4i) mod 8
// spreads the 20 octs across all 8 groups (round-15's stride-32 layout made
// bank-group independent of o -> 5-way conflicts, 11.8M cycles, the 55us).
__global__ __launch_bounds__(320) void caps_build2(
    const float* __restrict__ x, const float* __restrict__ w,
    unsigned short* __restrict__ u, float* __restrict__ psum)
{
    __shared__ float4 wl4[4][330];      // 4n x (10 o x 33) float4 = 21.1 KB
    const int t    = threadIdx.x;
    const int bloc = t / 20;            // 0..15
    const int oct  = t - bloc * 20;     // 0..19
    const int o    = oct >> 1;
    const int k8   = oct & 1;
    const int n0   = blockIdx.x * NTT;
    const int b    = blockIdx.y * BT2 + bloc;

    // staging decomposition of t (0..319 = one n-row's 320 float4)
    const int so = t >> 5;              // src o
    const int sr = t & 31;
    const int si = sr >> 2;             // src i
    const int sk = sr & 3;              // src kh
    const int sdst = so * 33 + si * 4 + sk;

    const float* xb = x + ((size_t)b * NIN + n0) * 8;
    unsigned short* ub = u + ((size_t)b * NIN + n0) * ROW + o * OL + k8 * 8;

    float ps[8];
    #pragma unroll
    for (int j = 0; j < 8; ++j) ps[j] = 0.f;

    for (int sub = 0; sub < 4; ++sub) {
        __syncthreads();
        // stage w for 4 n's: 1280 float4 / 320 thr, coalesced reads
        const float4* wg = reinterpret_cast<const float4*>(w)
                         + (size_t)(n0 + sub * 4) * 320;
        #pragma unroll
        for (int jj = 0; jj < 4; ++jj)
            wl4[jj][sdst] = wg[jj * 320 + t];
        __syncthreads();

        #pragma unroll
        for (int nn = 0; nn < 4; ++nn) {
            const int nrel = sub * 4 + nn;
            const float4 x0 = *reinterpret_cast<const float4*>(xb + nrel * 8);
            const float4 x1 = *reinterpret_cast<const float4*>(xb + nrel * 8 + 4);
            const float xv[IL] = {x0.x, x0.y, x0.z, x0.w, x1.x, x1.y, x1.z, x1.w};

            float acc[8];
            #pragma unroll
            for (int j = 0; j < 8; ++j) acc[j] = 0.f;

            const float4* wbase = &wl4[nn][o * 33 + k8 * 2];
            #pragma unroll
            for (int i = 0; i < IL; ++i) {
                const float4 wlo = wbase[i * 4];
                const float4 whi = wbase[i * 4 + 1];
                acc[0] = fmaf(wlo.x, xv[i], acc[0]);
                acc[1] = fmaf(wlo.y, xv[i], acc[1]);
                acc[2] = fmaf(wlo.z, xv[i], acc[2]);
                acc[3] = fmaf(wlo.w, xv[i], acc[3]);
                acc[4] = fmaf(whi.x, xv[i], acc[4]);
                acc[5] = fmaf(whi.y, xv[i], acc[5]);
                acc[6] = fmaf(whi.z, xv[i], acc[6]);
                acc[7] = fmaf(whi.w, xv[i], acc[7]);
            }

            union { ushx8 v; __hip_bfloat162 h[4]; } pk;
            #pragma unroll
            for (int j = 0; j < 4; ++j)
                pk.h[j] = __float22bfloat162_rn(make_float2(acc[2*j], acc[2*j+1]));
            *reinterpret_cast<ushx8*>(ub + (size_t)nrel * ROW) = pk.v;

            #pragma unroll
            for (int j = 0; j < 8; ++j) ps[j] += acc[j];
        }
    }

    float* pp = psum + ((size_t)blockIdx.x * BB + b) * ROW + oct * 8;
    *reinterpret_cast<float4*>(pp)     = make_float4(ps[0], ps[1], ps[2], ps[3]);
    *reinterpret_cast<float4*>(pp + 4) = make_float4(ps[4], ps[5], ps[6], ps[7]);
}

// K2: sum psum chunks, *0.1 + bias, squash -> v0. (verified round-15)
__global__ __launch_bounds__(192) void caps_squash0(
    const float* __restrict__ psum, const float* __restrict__ bias,
    float* __restrict__ v0)
{
    const int t = threadIdx.x;
    if (t >= ROW) return;
    const int b = blockIdx.x;

    float s0 = 0.f, s1 = 0.f, s2 = 0.f, s3 = 0.f;
    const float* pt = psum + (size_t)b * ROW + t;
    #pragma unroll
    for (int ch = 0; ch < NCH2; ch += 4) {
        s0 += pt[(size_t)(ch + 0) * BB * ROW];
        s1 += pt[(size_t)(ch + 1) * BB * ROW];
        s2 += pt[(size_t)(ch + 2) * BB * ROW];
        s3 += pt[(size_t)(ch + 3) * BB * ROW];
    }
    const float s = 0.1f * ((s0 + s1) + (s2 + s3)) + bias[t];

    float d = s * s;
    d += __shfl_xor(d, 1, 16);
    d += __shfl_xor(d, 2, 16);
    d += __shfl_xor(d, 4, 16);
    d += __shfl_xor(d, 8, 16);
    const float f = d / ((1.f + d) * sqrtf(d + EPSQ));
    v0[(size_t)b * ROW + t] = f * s;
}

// K3: routing iterations 1,2 fused (verified round-15 code, untouched).
__global__ __launch_bounds__(768) void caps_route2(
    const unsigned short* __restrict__ u, const float* __restrict__ bias,
    const float* __restrict__ v0g, float* __restrict__ outv)
{
    __shared__ float lds[12][ROW];
    __shared__ float vbuf[ROW];
    const int t  = threadIdx.x;
    const int q  = t & 3;
    const int g  = t >> 2;     // 0..191
    const int wv = t >> 6;     // 0..11
    const int b  = blockIdx.x;
    const unsigned short* ub = u + (size_t)b * NIN * ROW;

    float bsv = 0.f;
    float vprev = 0.f;
    if (t < ROW) {
        bsv = bias[t];
        const float v = v0g[(size_t)b * ROW + t];
        vbuf[t] = v;
        vprev = v;
    }
    __syncthreads();

    #pragma unroll
    for (int iter = 1; iter < 3; ++iter) {
        float sp[5][8];
        #pragma unroll
        for (int j = 0; j < 5; ++j)
            #pragma unroll
            for (int e = 0; e < 8; ++e) sp[j][e] = 0.f;

        float vs[5][8];
        #pragma unroll
        for (int j = 0; j < 5; ++j) {
            #pragma unroll
            for (int e = 0; e < 8; ++e) vs[j][e] = vbuf[(q + 4 * j) * 8 + e];
        }

        for (int m = 0; m < 6; ++m) {
            const unsigned short* un = ub + (size_t)(g + m * 192) * ROW;
            float uf[5][8];
            #pragma unroll
            for (int j = 0; j < 5; ++j) {
                const ushx8 raw = *reinterpret_cast<const ushx8*>(un + (q + 4 * j) * 8);
                #pragma unroll
                for (int e = 0; e < 8; ++e) uf[j][e] = bf2f(raw[e]);
            }

            // own-parity dots (half-k), combine halves, then swap parity
            float d[5], dd[5];
            #pragma unroll
            for (int j = 0; j < 5; ++j) {
                float acc = uf[j][0] * vs[j][0];
                #pragma unroll
                for (int e = 1; e < 8; ++e) acc = fmaf(uf[j][e], vs[j][e], acc);
                acc += __shfl_xor(acc, 1, 4);   // h=0 + h=1 -> full 16-k dot
                d[j] = acc;
            }
            #pragma unroll
            for (int j = 0; j < 5; ++j) dd[j] = __shfl_xor(d[j], 2, 4);

            float mx = fmaxf(d[0], dd[0]);
            #pragma unroll
            for (int j = 1; j < 5; ++j) mx = fmaxf(mx, fmaxf(d[j], dd[j]));
            float se = 0.f, e_[5];
            #pragma unroll
            for (int j = 0; j < 5; ++j) {
                e_[j] = __expf(d[j] - mx);
                se += e_[j] + __expf(dd[j] - mx);
            }
            const float r = 1.f / se;
            #pragma unroll
            for (int j = 0; j < 5; ++j) {
                const float c = e_[j] * r;
                #pragma unroll
                for (int e = 0; e < 8; ++e)
                    sp[j][e] = fmaf(c, uf[j][e], sp[j][e]);
            }
        }

        // butterfly over the 16 groups of each wave (masks preserve q)
        #pragma unroll
        for (int j = 0; j < 5; ++j)
            #pragma unroll
            for (int e = 0; e < 8; ++e) {
                #pragma unroll
                for (int msk = 4; msk <= 32; msk <<= 1)
                    sp[j][e] += __shfl_xor(sp[j][e], msk);
            }
        if ((t & 63) < 4) {
            #pragma unroll
            for (int j = 0; j < 5; ++j)
                #pragma unroll
                for (int e = 0; e < 8; ++e)
                    lds[wv][(q + 4 * j) * 8 + e] = sp[j][e];
        }
        __syncthreads();

        if (t < ROW) {
            float ssum = 0.f;
            #pragma unroll
            for (int wvi = 0; wvi < 12; ++wvi) ssum += lds[wvi][t];
            const float sv = ssum + bsv;

            float dq = sv * sv;
            dq += __shfl_xor(dq, 1, 16);
            dq += __shfl_xor(dq, 2, 16);
            dq += __shfl_xor(dq, 4, 16);
            dq += __shfl_xor(dq, 8, 16);
            const float f = dq / ((1.f + dq) * sqrtf(dq + EPSQ));
            const float v = f * sv;

            if (iter == 1) { vbuf[t] = v + vprev; }
            else           { outv[(size_t)b * ROW + t] = v; }
        }
        __syncthreads();
    }
}

extern "C" void kernel_launch(void* const* d_in, const int* in_sizes, int n_in,
                              void* d_out, int out_size, void* d_ws, size_t ws_size,
                              hipStream_t stream) {
    const float* x    = (const float*)d_in[0]; // (B, NIN, 8, 1)
    const float* w    = (const float*)d_in[1]; // (1, NIN, O, 8, 16)
    const float* bias = (const float*)d_in[2]; // (1, 1, O, 16, 1)
    float* out = (float*)d_out;                // (B, 1, O, 16, 1)

    unsigned short* u = (unsigned short*)d_ws;                  // 94.4 MB bf16
    float* psum = (float*)((char*)d_ws + (size_t)BB * NIN * ROW * 2); // 11.8 MB
    float* v0   = psum + (size_t)NCH2 * BB * ROW;               // 160 KB

    caps_build2<<<dim3(NIN / NTT, BB / BT2), 320, 0, stream>>>(x, w, u, psum);
    caps_squash0<<<BB, 192, 0, stream>>>(psum, bias, v0);
    caps_route2<<<BB, 768, 0, stream>>>(u, bias, v0, out);
}